// Round 15
// baseline (711.484 us; speedup 1.0000x reference)
//
#include <hip/hip_runtime.h>

// LGA3: 3 chained local-guided-aggregation passes, rolling-accumulator stencil.
// BARRIER-FREE wave-autonomous variant: each wave owns 8 disparities and stages
// its own 10-plane x 72-float cost window (d0-1..d0+8) into wave-private LDS,
// double-buffered via exactly-3 global_load_lds per row + counted s_waitcnt
// vmcnt(N) (no __syncthreads anywhere; FIFO retirement: stage issued before
// weights => any later weight wait also retires the stage).
// Weights: 75 per-thread global loads per iter (L1 absorbs cross-wave reuse).
// cost [B=2, D=64, H=384, W=768] fp32, weights [B, 75, H, W] fp32.
// out[b,d,h,w] = sum_{i,j in 5x5} w0*c[d-1,h+i-2,w+j-2] + w1*c[d,..] + w2*c[d+1,..]

#define B_ 2
#define D_ 64
#define H_ 384
#define W_ 768
static constexpr int HW    = H_ * W_;
static constexpr int DPT   = 8;           // disparities per thread
static constexpr int NTY   = 4;           // 4 waves/block (independent, no barriers)
static constexpr int WT    = 64;
static constexpr int HSEG  = 8;           // output rows per block
static constexpr int RITER = HSEG + 4;    // 12 streamed input rows
static constexpr int PLW   = 72;          // floats per plane row (w0-4 .. w0+67)
static constexpr int NPL   = 10;          // planes d0-1 .. d0+8 per wave
static constexpr int NGR   = NPL * 18;    // 180 real 16B granules per stage
static constexpr int BUFG  = 192;         // padded granules (3 instr x 64 lanes)
static constexpr int BUFF  = BUFG * 4;    // 768 floats per buffer

__device__ __forceinline__ void gld_lds16(const float* g, float* l) {
  __builtin_amdgcn_global_load_lds((const __attribute__((address_space(1))) unsigned int*)g,
                                   (__attribute__((address_space(3))) unsigned int*)l,
                                   16, 0, 0);
}

__global__ __launch_bounds__(256, 1) void lga_pass(const float* __restrict__ src,
                                                   const float* __restrict__ wts,
                                                   float* __restrict__ dst) {
  __shared__ float cl[NTY][2][BUFF];      // 24576 B, wave-private double buffers

  const int tx    = threadIdx.x;          // 0..63 (lane; wave = ty)
  const int ty    = threadIdx.y;          // 0..3
  const int bx    = blockIdx.x;
  const int w0    = bx * WT, w = w0 + tx;
  const int hs    = blockIdx.y * HSEG;
  const int b     = blockIdx.z >> 1;
  const int dhalf = blockIdx.z & 1;
  const int d0    = dhalf * 32 + ty * DPT;

  const float* sb  = src + (size_t)b * D_ * HW;
  const float* wtb = wts + (size_t)b * 75 * HW;

  const bool has_lo = (d0 > 0);
  const bool has_hi = (d0 + DPT < D_);
  const bool edge   = (bx == 0) || (bx == W_ / WT - 1);

  // wave-private stage of one input row: 3 gld_lds, lane-linear dest.
  // granule g -> plane p=g/18 (clamped source plane d0-1+p), 16B chunk k=g%18.
  auto stage = [&](int bufSel, int h_in) {
#pragma unroll
    for (int q = 0; q < 3; ++q) {
      int g = q * 64 + tx;
      g = g > NGR - 1 ? NGR - 1 : g;                // tail lanes -> slack granules
      const int p = g / 18;
      const int k = g - p * 18;
      int pd = d0 - 1 + p;
      pd = pd < 0 ? 0 : (pd > D_ - 1 ? D_ - 1 : pd);
      long idx = (long)pd * HW + (long)h_in * W_ + (w0 - 4) + (k << 2);
      idx = idx < 0 ? 0 : idx;
      const long mx = (long)D_ * HW - 4;
      idx = idx > mx ? mx : idx;
      gld_lds16(sb + idx, &cl[ty][bufSel][q * 256]);
    }
  };
  auto clampH = [](int h) { return h < 0 ? 0 : (h >= H_ ? H_ - 1 : h); };

  // prologue: stage row for iter 0 into buf 0, drain (wave-private)
  stage(0, clampH(hs - 2));
  asm volatile("s_waitcnt vmcnt(0)" ::: "memory");

  float acc[5][DPT];
#pragma unroll
  for (int s = 0; s < 5; ++s)
#pragma unroll
    for (int k = 0; k < DPT; ++k) acc[s][k] = 0.f;

#pragma unroll 1
  for (int r = 0; r < RITER; ++r) {
    // ---- 1. issue next-row stage FIRST (fence pins it before all later VMEM)
    if (r + 1 < RITER) stage((r + 1) & 1, clampH(hs - 2 + r + 1));
    asm volatile("" ::: "memory");

    // ---- 2. LDS -> vv from buf r&1 (stage r retired by last iter's wait)
    const int  h_in = hs - 2 + r;
    const bool hv   = (unsigned)h_in < (unsigned)H_;    // wave-uniform
    float vv[5][DPT + 2];
    if (hv) {
      const float* vb = &cl[ty][r & 1][0] + tx + 2;     // col = tx+j+2, plane m
      if (!edge) {
#pragma unroll
        for (int j = 0; j < 5; ++j)
#pragma unroll
          for (int m = 0; m < DPT + 2; ++m)
            vv[j][m] = vb[m * PLW + j];
        if (!has_lo) {
#pragma unroll
          for (int j = 0; j < 5; ++j) vv[j][0] = 0.f;
        }
        if (!has_hi) {
#pragma unroll
          for (int j = 0; j < 5; ++j) vv[j][DPT + 1] = 0.f;
        }
      } else {
#pragma unroll
        for (int j = 0; j < 5; ++j) {
          const bool wokj = (unsigned)(w + j - 2) < (unsigned)W_;
#pragma unroll
          for (int m = 0; m < DPT + 2; ++m) {
            const float v = vb[m * PLW + j];
            bool ok = wokj;
            if (m == 0)       ok = ok && has_lo;
            if (m == DPT + 1) ok = ok && has_hi;
            vv[j][m] = ok ? v : 0.f;
          }
        }
      }
    }

    // ---- 3. batch weight loads (75, uniform row bases; issued after the stage)
    float W[75];
#pragma unroll
    for (int s = 0; s < 5; ++s) {
      if ((unsigned)(r - 4 + s) < (unsigned)HSEG) {     // wave-uniform
        const int o     = hs + r - 4 + s;
        const int ib    = (4 - s) * 5;
        const float* wr = wtb + (size_t)o * W_;
#pragma unroll
        for (int g = 0; g < 3; ++g)
#pragma unroll
          for (int j = 0; j < 5; ++j)
            W[s * 15 + g * 5 + j] = wr[(size_t)(ib + j + 25 * g) * HW + w];
      }
    }

    // ---- 4. per-slot FMAs (slot s -> output row hs+r-4+s, tap row 4-s)
#pragma unroll
    for (int s = 0; s < 5; ++s) {
      if (hv && (unsigned)(r - 4 + s) < (unsigned)HSEG) {
#pragma unroll
        for (int j = 0; j < 5; ++j)
#pragma unroll
          for (int k = 0; k < DPT; ++k)
            acc[s][k] = fmaf(W[s * 15 + j],      vv[j][k],
                        fmaf(W[s * 15 + 5 + j],  vv[j][k + 1],
                        fmaf(W[s * 15 + 10 + j], vv[j][k + 2], acc[s][k])));
      }
    }

    // ---- 5. slot 0 complete -> write output row hs+r-4 (8 stores)
    if (r >= 4) {
      const int o = hs + r - 4;
#pragma unroll
      for (int k = 0; k < DPT; ++k) {
        float* dp = dst + (((size_t)b * D_ + d0 + k) * H_ + o) * W_;
        dp[w] = acc[0][k];
      }
    }

    // ---- 6. rotate accumulator slots (static indices)
#pragma unroll
    for (int s = 0; s < 4; ++s)
#pragma unroll
      for (int k = 0; k < DPT; ++k) acc[s][k] = acc[s + 1][k];
#pragma unroll
    for (int k = 0; k < DPT; ++k) acc[4][k] = 0.f;

    // ---- 7. wave-private end-of-iter wait: stage r+1 + weights retired;
    //         the 8 stores (youngest) may stay in flight. No barrier.
    if (r < RITER - 1) {
      if (r >= 4) { asm volatile("s_waitcnt vmcnt(8)" ::: "memory"); }
      else        { asm volatile("s_waitcnt vmcnt(0)" ::: "memory"); }
    }
  }
}

extern "C" void kernel_launch(void* const* d_in, const int* in_sizes, int n_in,
                              void* d_out, int out_size, void* d_ws, size_t ws_size,
                              hipStream_t stream) {
  const float* cost = (const float*)d_in[0];
  const float* wts  = (const float*)d_in[1];
  float* out = (float*)d_out;
  float* ws  = (float*)d_ws;

  dim3 grid(W_ / WT, H_ / HSEG, B_ * 2);   // 12 x 48 x 4 = 2304 blocks
  dim3 block(WT, NTY);                     // 64 x 4 = 256 threads, no barriers

  lga_pass<<<grid, block, 0, stream>>>(cost, wts, out);
  lga_pass<<<grid, block, 0, stream>>>(out, wts, ws);
  lga_pass<<<grid, block, 0, stream>>>(ws, wts, out);
}

// Round 16
// 594.458 us; speedup vs baseline: 1.1969x; 1.1969x over previous
//
#include <hip/hip_runtime.h>

// LGA3: 3 chained local-guided-aggregation passes, rolling-accumulator stencil.
// R13 d-split (4-wave independent 256-thr blocks, 32 d each) + FULL pipeline:
//   - weight slice (75ch x 64w) LDS DOUBLE-buffered, staged ONE ITERATION AHEAD
//     (5 global_load_lds per wave, issued right after the top barrier)
//   - cost tile single-buffered: vv hoisted at iter top, lgkmcnt(0)-fenced
//     mid barrier, then next row staged into the same buffer (3 chunks/wave)
//   - top barrier uses COUNTED s_waitcnt vmcnt(8) (stores = youngest 8 stay in
//     flight; never drains to 0 in the loop). Exact per-wave VMEM counts:
//     5 (w-stage) + 3 (c-stage) + 8 (stores), uniform via padded chunk counts.
// cost [B=2, D=64, H=384, W=768] fp32, weights [B, 75, H, W] fp32.
// out[b,d,h,w] = sum_{i,j in 5x5} w0*c[d-1,h+i-2,w+j-2] + w1*c[d,..] + w2*c[d+1,..]

#define B_ 2
#define D_ 64
#define H_ 384
#define W_ 768
static constexpr int HW    = H_ * W_;
static constexpr int DPT   = 8;           // disparities per thread
static constexpr int NTY   = 4;           // 4 waves/block -> 32 d per block
static constexpr int WT    = 64;
static constexpr int HSEG  = 8;           // output rows per block
static constexpr int RITER = HSEG + 4;    // 12 streamed input rows
static constexpr int PLW   = 72;          // floats per cost plane row (288 B)
static constexpr int LRWS  = 34;          // cost planes dbase..dbase+33
static constexpr int NGRAN = LRWS * 18;   // 612 real 16B granules per cost stage
static constexpr int NCH_C = 12;          // cost chunks (10 real + 2 pad) = 3/wave
static constexpr int NCH_W = 20;          // weight chunks (19 real + 1 pad) = 5/wave
static constexpr int CLF   = NCH_C * 256; // 3072 floats (12.0 KiB)
static constexpr int WLF   = NCH_W * 256; // 5120 floats (20.0 KiB per buffer)

__device__ __forceinline__ void gld_lds16(const float* g, float* l) {
  __builtin_amdgcn_global_load_lds((const __attribute__((address_space(1))) unsigned int*)g,
                                   (__attribute__((address_space(3))) unsigned int*)l,
                                   16, 0, 0);
}

__global__ __launch_bounds__(256, 1) void lga_pass(const float* __restrict__ src,
                                                   const float* __restrict__ wts,
                                                   float* __restrict__ dst) {
  __shared__ float cl[CLF];               // cost tile, single-buffered
  __shared__ float wl[2][WLF];            // weight slices, double-buffered

  const int tx    = threadIdx.x;          // 0..63 (lane; wave = ty)
  const int ty    = threadIdx.y;          // 0..3
  const int bx    = blockIdx.x;
  const int w0    = bx * WT, w = w0 + tx;
  const int hs    = blockIdx.y * HSEG;
  const int b     = blockIdx.z >> 1;
  const int dhalf = blockIdx.z & 1;
  const int dbase = dhalf * 32 - 1;       // plane held in cost LDS row 0
  const int d0    = dhalf * 32 + ty * DPT;

  const float* sb  = src + (size_t)b * D_ * HW;
  const float* wtb = wts + (size_t)b * 75 * HW;

  const bool has_lo = (d0 > 0);
  const bool has_hi = (d0 + DPT < D_);
  const bool edge   = (bx == 0) || (bx == W_ / WT - 1);

  // ---- cost stage: EXACTLY 3 gld_lds per wave (chunks ty, ty+4, ty+8)
  auto stage_c = [&](int h_in) {
#pragma unroll
    for (int q = 0; q < 3; ++q) {
      const int c = ty + q * 4;                     // 0..11, wave-uniform
      int G = c * 64 + tx;
      G = G > NGRAN - 1 ? NGRAN - 1 : G;            // pad/tail -> dup source
      const int p = G / 18;
      const int k = G - p * 18;
      int pd = dbase + p;
      pd = pd < 0 ? 0 : (pd > D_ - 1 ? D_ - 1 : pd);
      long idx = (long)pd * HW + (long)h_in * W_ + (w0 - 4) + (k << 2);
      idx = idx < 0 ? 0 : idx;
      const long mx = (long)D_ * HW - 4;
      idx = idx > mx ? mx : idx;
      gld_lds16(sb + idx, &cl[c * 256]);
    }
  };

  // ---- weight stage for iter rr into wl[rr&1]: EXACTLY 5 gld_lds per wave
  auto stage_w = [&](int rr) {
#pragma unroll
    for (int q = 0; q < 5; ++q) {
      const int ci = ty + q * 4;                    // 0..19, wave-uniform
      int ch = ci * 4 + (tx >> 4);
      ch = ch > 74 ? 74 : ch;                       // pad channels -> dup source
      const int s  = ch / 15;
      const int t  = ch - s * 15;
      const int g  = t / 5;
      const int j  = t - g * 5;
      const int cw = (4 - s) * 5 + j + g * 25;
      int o = hs + rr - 4 + s;
      o = o < 0 ? 0 : (o >= H_ ? H_ - 1 : o);       // clamped rows never consumed
      const float* p = wtb + (size_t)cw * HW + (size_t)o * W_ + w0 + ((tx & 15) << 2);
      gld_lds16(p, &wl[rr & 1][ci * 256]);
    }
  };

  auto clampH = [](int h) { return h < 0 ? 0 : (h >= H_ ? H_ - 1 : h); };

  // prologue: stage iter 0 (weights into wl[0], cost row hs-2 into cl)
  stage_w(0);
  stage_c(clampH(hs - 2));

  float acc[5][DPT];
#pragma unroll
  for (int s = 0; s < 5; ++s)
#pragma unroll
    for (int k = 0; k < DPT; ++k) acc[s][k] = 0.f;

#pragma unroll 1
  for (int r = 0; r < RITER; ++r) {
    // ---- 1. top barrier: my stage(r) loads retired (oldest 8); stores from
    //         r-1 (youngest 8) may remain in flight. Cross-wave via barrier.
    if (r <= 4) { asm volatile("s_waitcnt vmcnt(0)" ::: "memory"); }
    else        { asm volatile("s_waitcnt vmcnt(8)" ::: "memory"); }
    __builtin_amdgcn_s_barrier();
    __builtin_amdgcn_sched_barrier(0);

    // ---- 2. issue NEXT iter's weight stage immediately (full iter of slack)
    if (r + 1 < RITER) stage_w(r + 1);

    // ---- 3. hoist vv from cl (current row), with edge/d masks in registers
    const int  h_in = hs - 2 + r;
    const bool hv   = (unsigned)h_in < (unsigned)H_;   // block-uniform
    float vv[5][DPT + 2];
    if (hv) {
      const float* vb = cl + ty * DPT * PLW + tx + 2;
      if (!edge) {
#pragma unroll
        for (int j = 0; j < 5; ++j)
#pragma unroll
          for (int m = 0; m < DPT + 2; ++m)
            vv[j][m] = vb[m * PLW + j];
        if (!has_lo) {
#pragma unroll
          for (int j = 0; j < 5; ++j) vv[j][0] = 0.f;
        }
        if (!has_hi) {
#pragma unroll
          for (int j = 0; j < 5; ++j) vv[j][DPT + 1] = 0.f;
        }
      } else {
#pragma unroll
        for (int j = 0; j < 5; ++j) {
          const bool wokj = (unsigned)(w + j - 2) < (unsigned)W_;
#pragma unroll
          for (int m = 0; m < DPT + 2; ++m) {
            const float v = vb[m * PLW + j];
            bool ok = wokj;
            if (m == 0)       ok = ok && has_lo;
            if (m == DPT + 1) ok = ok && has_hi;
            vv[j][m] = ok ? v : 0.f;
          }
        }
      }
    }

    // ---- 4. mid barrier: all waves' cl reads retired -> safe to restage cl
    asm volatile("s_waitcnt lgkmcnt(0)" ::: "memory");
    __builtin_amdgcn_s_barrier();
    __builtin_amdgcn_sched_barrier(0);

    // ---- 5. issue next cost-row stage into the (single) cl buffer
    if (r + 1 < RITER) stage_c(clampH(hs - 2 + r + 1));

    // ---- 6. per-slot: 15 imm-offset weight ds_reads (wl[r&1]) + 120 FMAs
    const float* wcur = wl[r & 1];
#pragma unroll
    for (int s = 0; s < 5; ++s) {
      if (hv && (unsigned)(r - 4 + s) < (unsigned)HSEG) {  // block-uniform
        const float* wsl = wcur + s * 15 * 64 + tx;
#pragma unroll
        for (int j = 0; j < 5; ++j) {
          const float w0v = wsl[(j)      * 64];
          const float w1v = wsl[(5 + j)  * 64];
          const float w2v = wsl[(10 + j) * 64];
#pragma unroll
          for (int k = 0; k < DPT; ++k)
            acc[s][k] = fmaf(w0v, vv[j][k],
                        fmaf(w1v, vv[j][k + 1],
                        fmaf(w2v, vv[j][k + 2], acc[s][k])));
        }
      }
    }

    // ---- 7. slot 0 complete -> write output row hs+r-4 (8 stores, youngest)
    if (r >= 4) {
      const int o = hs + r - 4;
#pragma unroll
      for (int k = 0; k < DPT; ++k) {
        float* dp = dst + (((size_t)b * D_ + d0 + k) * H_ + o) * W_;
        dp[w] = acc[0][k];
      }
    }

    // ---- 8. rotate accumulator slots (static indices)
#pragma unroll
    for (int s = 0; s < 4; ++s)
#pragma unroll
      for (int k = 0; k < DPT; ++k) acc[s][k] = acc[s + 1][k];
#pragma unroll
    for (int k = 0; k < DPT; ++k) acc[4][k] = 0.f;
  }
}

extern "C" void kernel_launch(void* const* d_in, const int* in_sizes, int n_in,
                              void* d_out, int out_size, void* d_ws, size_t ws_size,
                              hipStream_t stream) {
  const float* cost = (const float*)d_in[0];
  const float* wts  = (const float*)d_in[1];
  float* out = (float*)d_out;
  float* ws  = (float*)d_ws;

  dim3 grid(W_ / WT, H_ / HSEG, B_ * 2);   // 12 x 48 x 4 = 2304 blocks
  dim3 block(WT, NTY);                     // 64 x 4 = 256 threads

  lga_pass<<<grid, block, 0, stream>>>(cost, wts, out);
  lga_pass<<<grid, block, 0, stream>>>(out, wts, ws);
  lga_pass<<<grid, block, 0, stream>>>(ws, wts, out);
}